// Round 1
// baseline (1067.027 us; speedup 1.0000x reference)
//
#include <hip/hip_runtime.h>
#include <stdint.h>

#define S_TOK 2048
#define D_NEU 11008
#define H_OUT 4096
#define K_TOK 3302
#define BASE_N 2201
#define K2_SEL 2201
#define NSEL 4402
#define NWORD 172          // D_NEU / 64

typedef __attribute__((ext_vector_type(8))) short short8;
typedef __attribute__((ext_vector_type(4))) short short4v;
typedef __attribute__((ext_vector_type(4))) float float4v;
typedef __attribute__((ext_vector_type(4))) unsigned int uint4v;
typedef unsigned long long u64;

__device__ __forceinline__ short f2bf(float x) {
  uint32_t u = __float_as_uint(x);
  u += 0x7FFFu + ((u >> 16) & 1u);
  return (short)(u >> 16);
}
__device__ __forceinline__ uint32_t fmap(float f) {
  uint32_t b = __float_as_uint(f);
  return (b & 0x80000000u) ? ~b : (b | 0x80000000u);
}

// ---------------- per-token exact top-k -> membership bitmask ----------------
// One block/token. v2: exact k-th largest via 4-pass 8-bit RADIX SELECT on the
// monotone-mapped uint32s held in LDS (replaces the 32-step bisection over a
// 44-register live array, which spilled/serialized: 425us at 13% VALU, 3% HBM).
// Per-wave privatized histograms with padded stride (N(0,1) concentrates ~29%
// of elements in one top-byte bin -> same-address LDS atomic serialization).
// Tie semantics identical to jax.lax.top_k (ties filled by lowest index).
__global__ __launch_bounds__(256) void topk_count(const float* __restrict__ x,
                                                  u64* __restrict__ bitmask,
                                                  short* __restrict__ xb) {
  __shared__ uint32_t u[D_NEU];     // 44032 B
  __shared__ int hist[4][264];      // per-wave hists; stride 264 de-banks copies
  __shared__ int bcast[4];
  const int t = blockIdx.x;
  const int tid = threadIdx.x;
  const int lane = tid & 63, wv = tid >> 6;
  const float* row = x + (size_t)t * D_NEU;

  // load + monotone-map into LDS; fused x -> bf16
  #pragma unroll
  for (int j = 0; j < 11; ++j) {
    int i4 = tid + j * 256;               // float4 index, 2752 total
    if (i4 < 2752) {
      float4v v = ((const float4v*)row)[i4];
      uint4v m;
      #pragma unroll
      for (int c = 0; c < 4; ++c) m[c] = fmap(v[c]);
      *(uint4v*)&u[i4 * 4] = m;
      if (xb) {
        short4v o;
        #pragma unroll
        for (int c = 0; c < 4; ++c) o[c] = f2bf(v[c]);
        *(short4v*)(xb + (size_t)t * D_NEU + i4 * 4) = o;
      }
    }
  }

  uint32_t prefix = 0;   // decided high bits of the k-th largest value
  int K = K_TOK;         // how many still needed at/below current prefix level
  int eq = 0;            // final pass: count of elements exactly == vstar
  #pragma unroll
  for (int pass = 0; pass < 4; ++pass) {
    const int shift = 24 - 8 * pass;
    for (int b = lane; b < 256; b += 64) hist[wv][b] = 0;
    __syncthreads();     // hist zeroed; (pass 0) u[] visible
    if (pass == 0) {
      #pragma unroll
      for (int j = 0; j < 11; ++j) {
        int i4 = tid + j * 256;
        if (i4 < 2752) {
          uint4v m = *(const uint4v*)&u[i4 * 4];
          #pragma unroll
          for (int c = 0; c < 4; ++c)
            atomicAdd(&hist[wv][m[c] >> 24], 1);
        }
      }
    } else {
      const uint32_t pm = 0xFFFFFFFFu << (shift + 8);
      #pragma unroll
      for (int j = 0; j < 11; ++j) {
        int i4 = tid + j * 256;
        if (i4 < 2752) {
          uint4v m = *(const uint4v*)&u[i4 * 4];
          #pragma unroll
          for (int c = 0; c < 4; ++c)
            if ((m[c] & pm) == prefix)
              atomicAdd(&hist[wv][(m[c] >> shift) & 255], 1);
        }
      }
    }
    __syncthreads();
    // wave 0: find bin b with SuffixSum(b) >= K > SuffixSum(b+1)
    if (wv == 0) {
      int h0 = hist[0][lane * 4 + 0] + hist[1][lane * 4 + 0] + hist[2][lane * 4 + 0] + hist[3][lane * 4 + 0];
      int h1 = hist[0][lane * 4 + 1] + hist[1][lane * 4 + 1] + hist[2][lane * 4 + 1] + hist[3][lane * 4 + 1];
      int h2 = hist[0][lane * 4 + 2] + hist[1][lane * 4 + 2] + hist[2][lane * 4 + 2] + hist[3][lane * 4 + 2];
      int h3 = hist[0][lane * 4 + 3] + hist[1][lane * 4 + 3] + hist[2][lane * 4 + 3] + hist[3][lane * 4 + 3];
      int s = h0 + h1 + h2 + h3;
      int suf = s;                         // inclusive suffix scan across lanes
      #pragma unroll
      for (int off = 1; off < 64; off <<= 1) {
        int o = __shfl_down(suf, off);
        if (lane + off < 64) suf += o;
      }
      int S4 = suf - s;                    // sum of bins >= 4*(lane+1)
      int S3 = h3 + S4;
      int S2 = h2 + S3;
      int S1 = h1 + S2;
      int S0 = h0 + S1;
      if (S0 >= K && S1 < K)      { bcast[0] = lane * 4 + 0; bcast[1] = K - S1; bcast[2] = h0; }
      else if (S1 >= K && S2 < K) { bcast[0] = lane * 4 + 1; bcast[1] = K - S2; bcast[2] = h1; }
      else if (S2 >= K && S3 < K) { bcast[0] = lane * 4 + 2; bcast[1] = K - S3; bcast[2] = h2; }
      else if (S3 >= K && S4 < K) { bcast[0] = lane * 4 + 3; bcast[1] = K - S4; bcast[2] = h3; }
    }
    __syncthreads();
    prefix |= ((uint32_t)bcast[0]) << shift;
    K = bcast[1];
    eq = bcast[2];
  }
  const uint32_t vstar = prefix;          // exact k-th largest (mapped)
  const int ties = K;                     // equals to include
  const bool tie_all = (ties == eq);

  // ballot membership: wave wv covers words [wv*43, wv*43+43)
  for (int w = wv * 43; w < wv * 43 + 43; ++w) {
    uint32_t uu = u[w * 64 + lane];
    bool m = false;
    if (uu > vstar) m = true;
    else if (uu == vstar) {
      if (tie_all) m = true;
      else {                              // rare exact-tie path
        int idx = w * 64 + lane, r = 0;
        for (int i = 0; i < idx; ++i) r += (u[i] == vstar) ? 1 : 0;
        m = (r < ties);
      }
    }
    u64 mask = __ballot(m);
    if (lane == 0) bitmask[(size_t)w * S_TOK + t] = mask;
  }
}

// ---------------- counts[d] = sum_t bit(t,d) ----------------
__global__ __launch_bounds__(256) void count_bits(const u64* __restrict__ bitmask,
                                                  int* __restrict__ counts) {
  __shared__ u64 m[S_TOK];        // 16 KB
  __shared__ int partial[4][64];
  const int w = blockIdx.x, tid = threadIdx.x;
  for (int i = tid; i < S_TOK; i += 256) m[i] = bitmask[(size_t)w * S_TOK + i];
  __syncthreads();
  const int b = tid & 63, part = tid >> 6;
  int c = 0;
  for (int t = part * 512; t < part * 512 + 512; ++t) c += (int)((m[t] >> b) & 1ull);
  partial[part][b] = c;
  __syncthreads();
  if (tid < 64)
    counts[w * 64 + tid] = partial[0][tid] + partial[1][tid] + partial[2][tid] + partial[3][tid];
}

// ---------------- rank candidates, select top-2201, emit idx_all ----------------
// keys are DISTINCT (count<<14 | reversed-id)+1, so the 2201st-largest key is
// found by bisection, the winners compacted, and only 4096 sorted bitonically.
__global__ __launch_bounds__(1024) void rank_select(const int* __restrict__ counts,
                                                    int* __restrict__ idx_all) {
  __shared__ uint32_t cand[4096];   // 16 KB
  __shared__ int red[16];
  __shared__ int cnt_sh;
  const int tid = threadIdx.x, lane = tid & 63, wv = tid >> 6;
  const int NC = D_NEU - BASE_N;    // 8807
  uint32_t kv[9];
  #pragma unroll
  for (int j = 0; j < 9; ++j) {
    int i = tid + j * 1024;
    kv[j] = 0u;
    if (i < NC) {
      int d = BASE_N + i;
      kv[j] = ((((uint32_t)counts[d]) << 14) | (uint32_t)(D_NEU - 1 - d)) + 1u;
    }
  }
  auto cnt_ge = [&](uint32_t T) -> int {
    int c = 0;
    #pragma unroll
    for (int j = 0; j < 9; ++j) c += (kv[j] >= T) ? 1 : 0;
    #pragma unroll
    for (int off = 32; off; off >>= 1) c += __shfl_down(c, off);
    if (lane == 0) red[wv] = c;
    __syncthreads();
    int tot = 0;
    #pragma unroll
    for (int k = 0; k < 16; ++k) tot += red[k];
    __syncthreads();
    return tot;
  };
  uint32_t lo = 0u, hi = 1u << 26;
  while (hi - lo > 1u) {
    uint32_t mid = lo + ((hi - lo) >> 1);
    if (cnt_ge(mid) >= K2_SEL) lo = mid; else hi = mid;
  }
  if (tid == 0) cnt_sh = 0;
  for (int i = tid; i < 4096; i += 1024) cand[i] = 0u;
  __syncthreads();
  #pragma unroll
  for (int j = 0; j < 9; ++j)
    if (kv[j] >= lo && kv[j] != 0u) { int p = atomicAdd(&cnt_sh, 1); cand[p] = kv[j]; }
  __syncthreads();
  // bitonic sort 4096 descending
  for (unsigned size = 2; size <= 4096u; size <<= 1) {
    for (unsigned stride = size >> 1; stride > 0; stride >>= 1) {
      #pragma unroll
      for (unsigned tt = tid; tt < 2048u; tt += 1024u) {
        unsigned li = ((tt & ~(stride - 1u)) << 1) | (tt & (stride - 1u));
        unsigned hi2 = li + stride;
        uint32_t a = cand[li], b = cand[hi2];
        bool desc = ((li & size) == 0u);
        if (desc ? (a < b) : (a > b)) { cand[li] = b; cand[hi2] = a; }
      }
      __syncthreads();
    }
  }
  for (int j = tid; j < BASE_N; j += 1024) idx_all[j] = j;
  for (int j = tid; j < K2_SEL; j += 1024)
    idx_all[BASE_N + j] = (D_NEU - 1) - (int)((cand[j] - 1u) & 0x3FFFu);
}

// ---------------- fused W pass: W->bf16 + gather filtered_W ----------------
__global__ __launch_bounds__(256) void fused_w(const float* __restrict__ W,
                                               const int* __restrict__ idx_all,
                                               short* __restrict__ Wb,
                                               float* __restrict__ out2) {
  __shared__ float row[D_NEU];    // 44 KB
  const int h = blockIdx.x, tid = threadIdx.x;
  const float* src = W + (size_t)h * D_NEU;
  #pragma unroll
  for (int j = 0; j < 11; ++j) {
    int i4 = tid + j * 256;
    if (i4 < 2752) {
      float4v v = ((const float4v*)src)[i4];
      *(float4v*)&row[i4 * 4] = v;
      if (Wb) {
        short4v o;
        #pragma unroll
        for (int c = 0; c < 4; ++c) o[c] = f2bf(v[c]);
        *(short4v*)(Wb + (size_t)h * D_NEU + i4 * 4) = o;
      }
    }
  }
  __syncthreads();
  for (int j = tid; j < NSEL; j += 256)
    out2[(size_t)h * NSEL + j] = row[idx_all[j]];
}

// ---------------- bf16 MFMA GEMM, split-K=2, XOR chunk-swizzle ----------------
#define BM 128
#define BN 128
#define BKK 32
#define KSPLIT 2
#define KHALF (D_NEU / KSPLIT)   // 5504 = 172 * 32

template <int FROM_FP32>
__global__ __launch_bounds__(256) void gemm_bt(const void* __restrict__ Av,
                                               const void* __restrict__ Bv,
                                               float* __restrict__ C) {
  __shared__ __align__(16) short As[BM * BKK];   // 8 KB
  __shared__ __align__(16) short Bs[BN * BKK];   // 8 KB
  const int tid = threadIdx.x;
  const int bm = blockIdx.y * BM;
  const int bn = blockIdx.x * BN;
  const int kz = blockIdx.z;
  const int wave = tid >> 6, lane = tid & 63;
  const int wm = (wave >> 1) * 64, wn = (wave & 1) * 64;
  const int quad = lane >> 4, l16 = lane & 15;
  float4v acc[4][4];
  #pragma unroll
  for (int i = 0; i < 4; ++i)
    #pragma unroll
    for (int j = 0; j < 4; ++j) acc[i][j] = (float4v){0.f, 0.f, 0.f, 0.f};

  const int kbeg = kz * KHALF, kend = kbeg + KHALF;
  for (int k0 = kbeg; k0 < kend; k0 += BKK) {
    #pragma unroll
    for (int c = 0; c < 2; ++c) {
      int f = tid + c * 256;            // LDS 16B-slot id (512/tile)
      int r = f >> 2, sl = f & 3;
      int cg = sl ^ (r & 3);            // swizzled global chunk
      if (FROM_FP32) {
        const float* A = (const float*)Av;
        const float* B = (const float*)Bv;
        float4v v0 = *(const float4v*)(A + (size_t)(bm + r) * D_NEU + k0 + cg * 8);
        float4v v1 = *(const float4v*)(A + (size_t)(bm + r) * D_NEU + k0 + cg * 8 + 4);
        short8 o;
        #pragma unroll
        for (int c2 = 0; c2 < 4; ++c2) { o[c2] = f2bf(v0[c2]); o[c2+4] = f2bf(v1[c2]); }
        *(short8*)&As[f * 8] = o;
        v0 = *(const float4v*)(B + (size_t)(bn + r) * D_NEU + k0 + cg * 8);
        v1 = *(const float4v*)(B + (size_t)(bn + r) * D_NEU + k0 + cg * 8 + 4);
        #pragma unroll
        for (int c2 = 0; c2 < 4; ++c2) { o[c2] = f2bf(v0[c2]); o[c2+4] = f2bf(v1[c2]); }
        *(short8*)&Bs[f * 8] = o;
      } else {
        const short* A = (const short*)Av;
        const short* B = (const short*)Bv;
        __builtin_amdgcn_global_load_lds(
            (const __attribute__((address_space(1))) void*)(A + (size_t)(bm + r) * D_NEU + k0 + cg * 8),
            (__attribute__((address_space(3))) void*)&As[f * 8], 16, 0, 0);
        __builtin_amdgcn_global_load_lds(
            (const __attribute__((address_space(1))) void*)(B + (size_t)(bn + r) * D_NEU + k0 + cg * 8),
            (__attribute__((address_space(3))) void*)&Bs[f * 8], 16, 0, 0);
      }
    }
    __syncthreads();
    short8 af[4], bfv[4];
    #pragma unroll
    for (int i = 0; i < 4; ++i) {
      int ra = wm + i * 16 + l16;
      int rb = wn + i * 16 + l16;
      af[i]  = *(const short8*)&As[(ra * 4 + (quad ^ (ra & 3))) * 8];
      bfv[i] = *(const short8*)&Bs[(rb * 4 + (quad ^ (rb & 3))) * 8];
    }
    #pragma unroll
    for (int i = 0; i < 4; ++i)
      #pragma unroll
      for (int j = 0; j < 4; ++j)
        acc[i][j] = __builtin_amdgcn_mfma_f32_16x16x32_bf16(af[i], bfv[j], acc[i][j], 0, 0, 0);
    __syncthreads();
  }
  // C/D layout: col = lane&15, row = quad*4 + reg  [m89-verified]
  #pragma unroll
  for (int i = 0; i < 4; ++i)
    #pragma unroll
    for (int j = 0; j < 4; ++j)
      #pragma unroll
      for (int r = 0; r < 4; ++r)
        unsafeAtomicAdd(
            &C[(size_t)(bm + wm + i * 16 + quad * 4 + r) * H_OUT + (bn + wn + j * 16 + l16)],
            acc[i][j][r]);
}

extern "C" void kernel_launch(void* const* d_in, const int* in_sizes, int n_in,
                              void* d_out, int out_size, void* d_ws, size_t ws_size,
                              hipStream_t stream) {
  (void)in_sizes; (void)n_in; (void)out_size;
  const float* x = (const float*)d_in[0];   // [1, 2048, 11008]
  const float* W = (const float*)d_in[1];   // [4096, 11008]
  float* out1 = (float*)d_out;                       // true_value [2048*4096]
  float* out2 = out1 + (size_t)S_TOK * H_OUT;        // filtered_W [4096*4402]

  uint8_t* ws = (uint8_t*)d_ws;
  int* idx_all = (int*)ws;                              // 17608 B
  int* counts  = (int*)(ws + 17664);                    // 44032 B
  short* xb = (short*)(ws + 65536);                     // 45,088,768 B
  short* Wb = xb + (size_t)S_TOK * D_NEU;               // 90,177,536 B
  const size_t needA = 65536 + ((size_t)S_TOK + H_OUT) * D_NEU * 2;
  const bool pathA = ws_size >= needA;
  // bitmask (2,818,048 B) aliases the Wb region: it is fully consumed by
  // count_bits before fused_w writes Wb (single in-order stream).
  u64* bitmask = pathA ? (u64*)Wb : (u64*)(ws + 65536);

  hipMemsetAsync(out1, 0, (size_t)S_TOK * H_OUT * sizeof(float), stream);
  topk_count<<<S_TOK, 256, 0, stream>>>(x, bitmask, pathA ? xb : nullptr);
  count_bits<<<NWORD, 256, 0, stream>>>(bitmask, counts);
  rank_select<<<1, 1024, 0, stream>>>(counts, idx_all);
  fused_w<<<H_OUT, 256, 0, stream>>>(W, idx_all, pathA ? Wb : nullptr, out2);
  if (pathA)
    gemm_bt<0><<<dim3(H_OUT / BN, S_TOK / BM, KSPLIT), 256, 0, stream>>>(xb, Wb, out1);
  else
    gemm_bt<1><<<dim3(H_OUT / BN, S_TOK / BM, KSPLIT), 256, 0, stream>>>(x, W, out1);
}

// Round 2
// 1033.615 us; speedup vs baseline: 1.0323x; 1.0323x over previous
//
#include <hip/hip_runtime.h>
#include <stdint.h>

#define S_TOK 2048
#define D_NEU 11008
#define H_OUT 4096
#define K_TOK 3302
#define BASE_N 2201
#define K2_SEL 2201
#define NSEL 4402
#define NWORD 172          // D_NEU / 64

typedef __attribute__((ext_vector_type(8))) short short8;
typedef __attribute__((ext_vector_type(4))) short short4v;
typedef __attribute__((ext_vector_type(4))) float float4v;
typedef __attribute__((ext_vector_type(4))) unsigned int uint4v;
typedef unsigned long long u64;

__device__ __forceinline__ short f2bf(float x) {
  uint32_t u = __float_as_uint(x);
  u += 0x7FFFu + ((u >> 16) & 1u);
  return (short)(u >> 16);
}
__device__ __forceinline__ uint32_t fmap(float f) {
  uint32_t b = __float_as_uint(f);
  return (b & 0x80000000u) ? ~b : (b | 0x80000000u);
}

// ---------------- per-token exact top-k -> membership bitmask ----------------
// One block/token. v3: same exact 4-pass radix select as v2, but 1024 threads
// per token (16 waves). v1 (bisection) and v2 (radix) both measured 427us with
// identical duration despite totally different inner loops -> the bottleneck is
// the per-block barrier-separated critical path at ~2.4 waves/CU occupancy,
// not the arithmetic. 4x waves/block cuts the serial path 4x and raises
// resident waves/CU 4-13x. Radix values live in statically-indexed registers
// (<=12 scalars/thread); u[] kept only for the ballot phase + rare-tie path.
// Tie semantics identical to jax.lax.top_k (ties filled by lowest index).
__global__ __launch_bounds__(1024) void topk_count(const float* __restrict__ x,
                                                   u64* __restrict__ bitmask,
                                                   short* __restrict__ xb) {
  __shared__ uint32_t u[D_NEU];     // 44032 B
  __shared__ int hist[16][257];     // 16448 B; stride 257 de-banks the copies
  __shared__ int bcast[4];
  const int t = blockIdx.x;
  const int tid = threadIdx.x;
  const int lane = tid & 63, wv = tid >> 6;
  const float* row = x + (size_t)t * D_NEU;

  // load + monotone-map into LDS + registers; fused x -> bf16
  uint32_t mv[12];
  #pragma unroll
  for (int j = 0; j < 3; ++j) {
    int i4 = tid + j * 1024;              // float4 index, 2752 total
    if (i4 < 2752) {
      float4v v = ((const float4v*)row)[i4];
      uint4v m;
      #pragma unroll
      for (int c = 0; c < 4; ++c) { m[c] = fmap(v[c]); mv[j * 4 + c] = m[c]; }
      *(uint4v*)&u[i4 * 4] = m;
      if (xb) {
        short4v o;
        #pragma unroll
        for (int c = 0; c < 4; ++c) o[c] = f2bf(v[c]);
        *(short4v*)(xb + (size_t)t * D_NEU + i4 * 4) = o;
      }
    }
  }

  uint32_t prefix = 0;   // decided high bits of the k-th largest value
  int K = K_TOK;         // how many still needed at/below current prefix level
  int eq = 0;            // final pass: count of elements exactly == vstar
  int* hf = &hist[0][0];
  #pragma unroll
  for (int pass = 0; pass < 4; ++pass) {
    const int shift = 24 - 8 * pass;
    for (int b = tid; b < 16 * 257; b += 1024) hf[b] = 0;
    __syncthreads();     // hist zeroed
    if (pass == 0) {
      #pragma unroll
      for (int j = 0; j < 3; ++j) {
        if (tid + j * 1024 < 2752) {
          #pragma unroll
          for (int c = 0; c < 4; ++c)
            atomicAdd(&hist[wv][mv[j * 4 + c] >> 24], 1);
        }
      }
    } else {
      const uint32_t pm = 0xFFFFFFFFu << (shift + 8);
      #pragma unroll
      for (int j = 0; j < 3; ++j) {
        if (tid + j * 1024 < 2752) {
          #pragma unroll
          for (int c = 0; c < 4; ++c)
            if ((mv[j * 4 + c] & pm) == prefix)
              atomicAdd(&hist[wv][(mv[j * 4 + c] >> shift) & 255], 1);
        }
      }
    }
    __syncthreads();
    // wave 0: find bin b with SuffixSum(b) >= K > SuffixSum(b+1)
    if (wv == 0) {
      int h0 = 0, h1 = 0, h2 = 0, h3 = 0;
      #pragma unroll
      for (int c = 0; c < 16; ++c) {
        h0 += hist[c][lane * 4 + 0];
        h1 += hist[c][lane * 4 + 1];
        h2 += hist[c][lane * 4 + 2];
        h3 += hist[c][lane * 4 + 3];
      }
      int s = h0 + h1 + h2 + h3;
      int suf = s;                         // inclusive suffix scan across lanes
      #pragma unroll
      for (int off = 1; off < 64; off <<= 1) {
        int o = __shfl_down(suf, off);
        if (lane + off < 64) suf += o;
      }
      int S4 = suf - s;                    // sum of bins >= 4*(lane+1)
      int S3 = h3 + S4;
      int S2 = h2 + S3;
      int S1 = h1 + S2;
      int S0 = h0 + S1;
      if (S0 >= K && S1 < K)      { bcast[0] = lane * 4 + 0; bcast[1] = K - S1; bcast[2] = h0; }
      else if (S1 >= K && S2 < K) { bcast[0] = lane * 4 + 1; bcast[1] = K - S2; bcast[2] = h1; }
      else if (S2 >= K && S3 < K) { bcast[0] = lane * 4 + 2; bcast[1] = K - S3; bcast[2] = h2; }
      else if (S3 >= K && S4 < K) { bcast[0] = lane * 4 + 3; bcast[1] = K - S4; bcast[2] = h3; }
    }
    __syncthreads();
    prefix |= ((uint32_t)bcast[0]) << shift;
    K = bcast[1];
    eq = bcast[2];
  }
  const uint32_t vstar = prefix;          // exact k-th largest (mapped)
  const int ties = K;                     // equals to include
  const bool tie_all = (ties == eq);

  // ballot membership: waves stride across the 172 words
  for (int w = wv; w < NWORD; w += 16) {
    uint32_t uu = u[w * 64 + lane];
    bool m = false;
    if (uu > vstar) m = true;
    else if (uu == vstar) {
      if (tie_all) m = true;
      else {                              // rare exact-tie path
        int idx = w * 64 + lane, r = 0;
        for (int i = 0; i < idx; ++i) r += (u[i] == vstar) ? 1 : 0;
        m = (r < ties);
      }
    }
    u64 mask = __ballot(m);
    if (lane == 0) bitmask[(size_t)w * S_TOK + t] = mask;
  }
}

// ---------------- counts[d] = sum_t bit(t,d) ----------------
__global__ __launch_bounds__(256) void count_bits(const u64* __restrict__ bitmask,
                                                  int* __restrict__ counts) {
  __shared__ u64 m[S_TOK];        // 16 KB
  __shared__ int partial[4][64];
  const int w = blockIdx.x, tid = threadIdx.x;
  for (int i = tid; i < S_TOK; i += 256) m[i] = bitmask[(size_t)w * S_TOK + i];
  __syncthreads();
  const int b = tid & 63, part = tid >> 6;
  int c = 0;
  for (int t = part * 512; t < part * 512 + 512; ++t) c += (int)((m[t] >> b) & 1ull);
  partial[part][b] = c;
  __syncthreads();
  if (tid < 64)
    counts[w * 64 + tid] = partial[0][tid] + partial[1][tid] + partial[2][tid] + partial[3][tid];
}

// ---------------- rank candidates, select top-2201, emit idx_all ----------------
// keys are DISTINCT (count<<14 | reversed-id)+1, so the 2201st-largest key is
// found by bisection, the winners compacted, and only 4096 sorted bitonically.
__global__ __launch_bounds__(1024) void rank_select(const int* __restrict__ counts,
                                                    int* __restrict__ idx_all) {
  __shared__ uint32_t cand[4096];   // 16 KB
  __shared__ int red[16];
  __shared__ int cnt_sh;
  const int tid = threadIdx.x, lane = tid & 63, wv = tid >> 6;
  const int NC = D_NEU - BASE_N;    // 8807
  uint32_t kv[9];
  #pragma unroll
  for (int j = 0; j < 9; ++j) {
    int i = tid + j * 1024;
    kv[j] = 0u;
    if (i < NC) {
      int d = BASE_N + i;
      kv[j] = ((((uint32_t)counts[d]) << 14) | (uint32_t)(D_NEU - 1 - d)) + 1u;
    }
  }
  auto cnt_ge = [&](uint32_t T) -> int {
    int c = 0;
    #pragma unroll
    for (int j = 0; j < 9; ++j) c += (kv[j] >= T) ? 1 : 0;
    #pragma unroll
    for (int off = 32; off; off >>= 1) c += __shfl_down(c, off);
    if (lane == 0) red[wv] = c;
    __syncthreads();
    int tot = 0;
    #pragma unroll
    for (int k = 0; k < 16; ++k) tot += red[k];
    __syncthreads();
    return tot;
  };
  uint32_t lo = 0u, hi = 1u << 26;
  while (hi - lo > 1u) {
    uint32_t mid = lo + ((hi - lo) >> 1);
    if (cnt_ge(mid) >= K2_SEL) lo = mid; else hi = mid;
  }
  if (tid == 0) cnt_sh = 0;
  for (int i = tid; i < 4096; i += 1024) cand[i] = 0u;
  __syncthreads();
  #pragma unroll
  for (int j = 0; j < 9; ++j)
    if (kv[j] >= lo && kv[j] != 0u) { int p = atomicAdd(&cnt_sh, 1); cand[p] = kv[j]; }
  __syncthreads();
  // bitonic sort 4096 descending
  for (unsigned size = 2; size <= 4096u; size <<= 1) {
    for (unsigned stride = size >> 1; stride > 0; stride >>= 1) {
      #pragma unroll
      for (unsigned tt = tid; tt < 2048u; tt += 1024u) {
        unsigned li = ((tt & ~(stride - 1u)) << 1) | (tt & (stride - 1u));
        unsigned hi2 = li + stride;
        uint32_t a = cand[li], b = cand[hi2];
        bool desc = ((li & size) == 0u);
        if (desc ? (a < b) : (a > b)) { cand[li] = b; cand[hi2] = a; }
      }
      __syncthreads();
    }
  }
  for (int j = tid; j < BASE_N; j += 1024) idx_all[j] = j;
  for (int j = tid; j < K2_SEL; j += 1024)
    idx_all[BASE_N + j] = (D_NEU - 1) - (int)((cand[j] - 1u) & 0x3FFFu);
}

// ---------------- fused W pass: W->bf16 + gather filtered_W ----------------
__global__ __launch_bounds__(256) void fused_w(const float* __restrict__ W,
                                               const int* __restrict__ idx_all,
                                               short* __restrict__ Wb,
                                               float* __restrict__ out2) {
  __shared__ float row[D_NEU];    // 44 KB
  const int h = blockIdx.x, tid = threadIdx.x;
  const float* src = W + (size_t)h * D_NEU;
  #pragma unroll
  for (int j = 0; j < 11; ++j) {
    int i4 = tid + j * 256;
    if (i4 < 2752) {
      float4v v = ((const float4v*)src)[i4];
      *(float4v*)&row[i4 * 4] = v;
      if (Wb) {
        short4v o;
        #pragma unroll
        for (int c = 0; c < 4; ++c) o[c] = f2bf(v[c]);
        *(short4v*)(Wb + (size_t)h * D_NEU + i4 * 4) = o;
      }
    }
  }
  __syncthreads();
  for (int j = tid; j < NSEL; j += 256)
    out2[(size_t)h * NSEL + j] = row[idx_all[j]];
}

// ---------------- bf16 MFMA GEMM, split-K=2, XOR chunk-swizzle ----------------
#define BM 128
#define BN 128
#define BKK 32
#define KSPLIT 2
#define KHALF (D_NEU / KSPLIT)   // 5504 = 172 * 32

template <int FROM_FP32>
__global__ __launch_bounds__(256) void gemm_bt(const void* __restrict__ Av,
                                               const void* __restrict__ Bv,
                                               float* __restrict__ C) {
  __shared__ __align__(16) short As[BM * BKK];   // 8 KB
  __shared__ __align__(16) short Bs[BN * BKK];   // 8 KB
  const int tid = threadIdx.x;
  const int bm = blockIdx.y * BM;
  const int bn = blockIdx.x * BN;
  const int kz = blockIdx.z;
  const int wave = tid >> 6, lane = tid & 63;
  const int wm = (wave >> 1) * 64, wn = (wave & 1) * 64;
  const int quad = lane >> 4, l16 = lane & 15;
  float4v acc[4][4];
  #pragma unroll
  for (int i = 0; i < 4; ++i)
    #pragma unroll
    for (int j = 0; j < 4; ++j) acc[i][j] = (float4v){0.f, 0.f, 0.f, 0.f};

  const int kbeg = kz * KHALF, kend = kbeg + KHALF;
  for (int k0 = kbeg; k0 < kend; k0 += BKK) {
    #pragma unroll
    for (int c = 0; c < 2; ++c) {
      int f = tid + c * 256;            // LDS 16B-slot id (512/tile)
      int r = f >> 2, sl = f & 3;
      int cg = sl ^ (r & 3);            // swizzled global chunk
      if (FROM_FP32) {
        const float* A = (const float*)Av;
        const float* B = (const float*)Bv;
        float4v v0 = *(const float4v*)(A + (size_t)(bm + r) * D_NEU + k0 + cg * 8);
        float4v v1 = *(const float4v*)(A + (size_t)(bm + r) * D_NEU + k0 + cg * 8 + 4);
        short8 o;
        #pragma unroll
        for (int c2 = 0; c2 < 4; ++c2) { o[c2] = f2bf(v0[c2]); o[c2+4] = f2bf(v1[c2]); }
        *(short8*)&As[f * 8] = o;
        v0 = *(const float4v*)(B + (size_t)(bn + r) * D_NEU + k0 + cg * 8);
        v1 = *(const float4v*)(B + (size_t)(bn + r) * D_NEU + k0 + cg * 8 + 4);
        #pragma unroll
        for (int c2 = 0; c2 < 4; ++c2) { o[c2] = f2bf(v0[c2]); o[c2+4] = f2bf(v1[c2]); }
        *(short8*)&Bs[f * 8] = o;
      } else {
        const short* A = (const short*)Av;
        const short* B = (const short*)Bv;
        __builtin_amdgcn_global_load_lds(
            (const __attribute__((address_space(1))) void*)(A + (size_t)(bm + r) * D_NEU + k0 + cg * 8),
            (__attribute__((address_space(3))) void*)&As[f * 8], 16, 0, 0);
        __builtin_amdgcn_global_load_lds(
            (const __attribute__((address_space(1))) void*)(B + (size_t)(bn + r) * D_NEU + k0 + cg * 8),
            (__attribute__((address_space(3))) void*)&Bs[f * 8], 16, 0, 0);
      }
    }
    __syncthreads();
    short8 af[4], bfv[4];
    #pragma unroll
    for (int i = 0; i < 4; ++i) {
      int ra = wm + i * 16 + l16;
      int rb = wn + i * 16 + l16;
      af[i]  = *(const short8*)&As[(ra * 4 + (quad ^ (ra & 3))) * 8];
      bfv[i] = *(const short8*)&Bs[(rb * 4 + (quad ^ (rb & 3))) * 8];
    }
    #pragma unroll
    for (int i = 0; i < 4; ++i)
      #pragma unroll
      for (int j = 0; j < 4; ++j)
        acc[i][j] = __builtin_amdgcn_mfma_f32_16x16x32_bf16(af[i], bfv[j], acc[i][j], 0, 0, 0);
    __syncthreads();
  }
  // C/D layout: col = lane&15, row = quad*4 + reg  [m89-verified]
  #pragma unroll
  for (int i = 0; i < 4; ++i)
    #pragma unroll
    for (int j = 0; j < 4; ++j)
      #pragma unroll
      for (int r = 0; r < 4; ++r)
        unsafeAtomicAdd(
            &C[(size_t)(bm + wm + i * 16 + quad * 4 + r) * H_OUT + (bn + wn + j * 16 + l16)],
            acc[i][j][r]);
}

extern "C" void kernel_launch(void* const* d_in, const int* in_sizes, int n_in,
                              void* d_out, int out_size, void* d_ws, size_t ws_size,
                              hipStream_t stream) {
  (void)in_sizes; (void)n_in; (void)out_size;
  const float* x = (const float*)d_in[0];   // [1, 2048, 11008]
  const float* W = (const float*)d_in[1];   // [4096, 11008]
  float* out1 = (float*)d_out;                       // true_value [2048*4096]
  float* out2 = out1 + (size_t)S_TOK * H_OUT;        // filtered_W [4096*4402]

  uint8_t* ws = (uint8_t*)d_ws;
  int* idx_all = (int*)ws;                              // 17608 B
  int* counts  = (int*)(ws + 17664);                    // 44032 B
  short* xb = (short*)(ws + 65536);                     // 45,088,768 B
  short* Wb = xb + (size_t)S_TOK * D_NEU;               // 90,177,536 B
  const size_t needA = 65536 + ((size_t)S_TOK + H_OUT) * D_NEU * 2;
  const bool pathA = ws_size >= needA;
  // bitmask (2,818,048 B) aliases the Wb region: it is fully consumed by
  // count_bits before fused_w writes Wb (single in-order stream).
  u64* bitmask = pathA ? (u64*)Wb : (u64*)(ws + 65536);

  hipMemsetAsync(out1, 0, (size_t)S_TOK * H_OUT * sizeof(float), stream);
  topk_count<<<S_TOK, 1024, 0, stream>>>(x, bitmask, pathA ? xb : nullptr);
  count_bits<<<NWORD, 256, 0, stream>>>(bitmask, counts);
  rank_select<<<1, 1024, 0, stream>>>(counts, idx_all);
  fused_w<<<H_OUT, 256, 0, stream>>>(W, idx_all, pathA ? Wb : nullptr, out2);
  if (pathA)
    gemm_bt<0><<<dim3(H_OUT / BN, S_TOK / BM, KSPLIT), 256, 0, stream>>>(xb, Wb, out1);
  else
    gemm_bt<1><<<dim3(H_OUT / BN, S_TOK / BM, KSPLIT), 256, 0, stream>>>(x, W, out1);
}